// Round 1
// baseline (855.318 us; speedup 1.0000x reference)
//
#include <hip/hip_runtime.h>
#include <math.h>

#define NB 32        // batches
#define NP 512       // N == M == 512
#define RG 8         // row-groups (blocks) per batch
#define RPB 64       // rows per block
#define ITERS 50
#define NEGV  -1e9f
#define EPSV   0.05f
#define INVEPS 20.0f

// ws layout in floats
#define WS_LOGA 0
#define WS_LOGB (NB*NP)                    // 16384
#define WS_HUB  (2*NB*NP)                  // 32768 (32 used, pad to 64)
#define WS_PART (2*NB*NP + 64)             // 32832: [2][NB][RG][NP][2] floats
#define PART_FLOATS (2*NB*RG*NP*2)         // 524288
#define WS_CTR  (WS_PART + PART_FLOATS)    // 32 ints live here

// ---------------- setup: loga/logb/huber, zero out + barrier counters ----------------
__global__ __launch_bounds__(NP) void setup_kernel(
    const float* __restrict__ a_mask, const float* __restrict__ pc_a,
    const float* __restrict__ b_mask, const float* __restrict__ pc_b,
    float* __restrict__ ws, float* __restrict__ out)
{
  __shared__ float scratch[16];
  const int b = blockIdx.x, t = threadIdx.x;
  const float apt = a_mask[b*NP+t] * pc_a[(b*NP+t)*3+2];
  const float bpt = b_mask[b*NP+t] * pc_b[(b*NP+t)*3+2];
  float ra = apt, rb = bpt;
  #pragma unroll
  for (int o = 32; o; o >>= 1) { ra += __shfl_xor(ra, o); rb += __shfl_xor(rb, o); }
  const int wid = t >> 6, lane = t & 63;
  if (lane == 0) { scratch[wid] = ra; scratch[8+wid] = rb; }
  __syncthreads();
  float asum = 0.f, bsum = 0.f;
  #pragma unroll
  for (int w = 0; w < 8; ++w) { asum += scratch[w]; bsum += scratch[8+w]; }

  ws[WS_LOGA + b*NP + t] = (apt > 0.f) ? __logf(apt/asum) : NEGV;
  ws[WS_LOGB + b*NP + t] = (bpt > 0.f) ? __logf(bpt/bsum) : NEGV;
  if (t == 0) {
    const float e = asum - bsum, ae = fabsf(e);
    ws[WS_HUB + b] = (ae <= 1.f) ? 0.5f*e*e : (ae - 0.5f);
    ((int*)(ws + WS_CTR))[b] = 0;
    out[b] = 0.f;
  }
}

// ---------------- main: 50 Sinkhorn iterations + flow/ot ----------------
__global__ __launch_bounds__(NP, 2) void sinkhorn_kernel(
    const float* __restrict__ pc_a, const float* __restrict__ pc_b,
    float* __restrict__ ws, float* __restrict__ out)
{
  const int b  = blockIdx.x & 31;   // batch: blocks {b, b+32, ...} share XCD (blockIdx%8 == b%8)
  const int rg = blockIdx.x >> 5;   // row-group 0..7
  const int t  = threadIdx.x;
  const int chunk = t & 7;          // row-phase column chunk
  const int lrow  = t >> 3;         // row-phase local row (0..63)
  const int grow  = rg*RPB + lrow;  // row within batch

  const float* loga = ws + WS_LOGA + (size_t)b*NP;
  const float* logb = ws + WS_LOGB + (size_t)b*NP;
  float* parts = ws + WS_PART;
  int*   ctr   = (int*)(ws + WS_CTR);

  __shared__ __align__(16) float g_lds[NP];
  __shared__ __align__(16) float logb_lds[NP];
  __shared__ __align__(16) float f_lds[RPB];
  __shared__ __align__(16) float loga_lds[RPB];
  __shared__ __align__(16) float sm[NP];
  __shared__ __align__(16) float ss[NP];

  logb_lds[t] = logb[t];
  if (t < RPB) loga_lds[t] = loga[rg*RPB + t];

  // ---- register cache of logK: row slice (row = grow, cols = 32*cc + 4*chunk + e)
  const float ax = pc_a[((size_t)b*NP+grow)*3+0];
  const float ay = pc_a[((size_t)b*NP+grow)*3+1];
  const bool  va = loga[grow] > -1e8f;
  float4 Kreg[16];
  #pragma unroll
  for (int cc = 0; cc < 16; ++cc) {
    float r[4];
    #pragma unroll
    for (int e = 0; e < 4; ++e) {
      const int col = 32*cc + 4*chunk + e;
      const float bx = pc_b[((size_t)b*NP+col)*3+0];
      const float by = pc_b[((size_t)b*NP+col)*3+1];
      const bool  vb = logb[col] > -1e8f;
      const float dx = ax-bx, dy = ay-by;
      const float d  = sqrtf(dx*dx + dy*dy + 1e-12f);
      r[e] = (va && vb) ? (-INVEPS)*d : 0.f;
    }
    Kreg[cc] = make_float4(r[0], r[1], r[2], r[3]);
  }
  // ---- register cache: column slice (col = t, rows rg*64 + i)
  const float bx0 = pc_b[((size_t)b*NP+t)*3+0];
  const float by0 = pc_b[((size_t)b*NP+t)*3+1];
  const bool  vb0 = logb[t] > -1e8f;
  float Kcol[RPB];
  #pragma unroll
  for (int i = 0; i < RPB; ++i) {
    const int row = rg*RPB + i;
    const float axi = pc_a[((size_t)b*NP+row)*3+0];   // uniform -> scalar loads
    const float ayi = pc_a[((size_t)b*NP+row)*3+1];
    const bool  vai = loga[row] > -1e8f;
    const float dx = axi-bx0, dy = ayi-by0;
    const float d  = sqrtf(dx*dx + dy*dy + 1e-12f);
    Kcol[i] = (vai && vb0) ? (-INVEPS)*d : 0.f;
  }
  __syncthreads();

  const float4* g4p = (const float4*)g_lds;
  const float4* f4p = (const float4*)f_lds;
  const float4* sm4 = (const float4*)sm;
  const float4* ss4 = (const float4*)ss;

  for (int k = 1; k <= ITERS+1; ++k) {
    // ---- combine column partials -> g_lds (logv); k==1: logv = 0
    if (k == 1) {
      g_lds[t] = 0.f;
    } else {
      const int parity = (k-1) & 1;
      const float2* pp = (const float2*)(parts) + (((size_t)parity*NB + b)*RG)*NP + t;
      float2 pr[RG];
      #pragma unroll
      for (int r = 0; r < RG; ++r) pr[r] = pp[(size_t)r*NP];
      float M = pr[0].x;
      #pragma unroll
      for (int r = 1; r < RG; ++r) M = fmaxf(M, pr[r].x);
      float S = 0.f;
      #pragma unroll
      for (int r = 0; r < RG; ++r) S += pr[r].y * __expf(pr[r].x - M);
      g_lds[t] = logb_lds[t] - (M + __logf(S));
    }
    __syncthreads();
    if (k == ITERS+1) break;   // g_lds now holds final logv

    // ---- row phase: f_i = loga_i - lse_j(logK + g)
    float m = -3.0e38f;
    #pragma unroll
    for (int cc = 0; cc < 16; ++cc) {
      const float4 g4 = g4p[8*cc + chunk];
      const float4 kk = Kreg[cc];
      m = fmaxf(m, fmaxf(fmaxf(kk.x+g4.x, kk.y+g4.y), fmaxf(kk.z+g4.z, kk.w+g4.w)));
    }
    sm[t] = m;
    __syncthreads();
    const float4 m0 = sm4[lrow*2+0], m1 = sm4[lrow*2+1];
    const float mrow = fmaxf(fmaxf(fmaxf(m0.x,m0.y),fmaxf(m0.z,m0.w)),
                             fmaxf(fmaxf(m1.x,m1.y),fmaxf(m1.z,m1.w)));
    float s = 0.f;
    #pragma unroll
    for (int cc = 0; cc < 16; ++cc) {
      const float4 g4 = g4p[8*cc + chunk];
      const float4 kk = Kreg[cc];
      s += __expf(kk.x+g4.x-mrow) + __expf(kk.y+g4.y-mrow)
         + __expf(kk.z+g4.z-mrow) + __expf(kk.w+g4.w-mrow);
    }
    ss[t] = s;
    __syncthreads();
    if (t < RPB) {
      const float4 s0 = ss4[t*2+0], s1 = ss4[t*2+1];
      const float4 q0 = sm4[t*2+0], q1 = sm4[t*2+1];
      const float mr = fmaxf(fmaxf(fmaxf(q0.x,q0.y),fmaxf(q0.z,q0.w)),
                             fmaxf(fmaxf(q1.x,q1.y),fmaxf(q1.z,q1.w)));
      const float sr = ((s0.x+s0.y)+(s0.z+s0.w)) + ((s1.x+s1.y)+(s1.z+s1.w));
      f_lds[t] = loga_lds[t] - (mr + __logf(sr));
    }
    __syncthreads();

    // ---- col phase: exact per-block (m,s) partial for column t
    float mc = -3.0e38f;
    #pragma unroll
    for (int i4 = 0; i4 < 16; ++i4) {
      const float4 ff = f4p[i4];
      mc = fmaxf(mc, fmaxf(fmaxf(Kcol[4*i4+0]+ff.x, Kcol[4*i4+1]+ff.y),
                           fmaxf(Kcol[4*i4+2]+ff.z, Kcol[4*i4+3]+ff.w)));
    }
    float sc = 0.f;
    #pragma unroll
    for (int i4 = 0; i4 < 16; ++i4) {
      const float4 ff = f4p[i4];
      sc += __expf(Kcol[4*i4+0]+ff.x-mc) + __expf(Kcol[4*i4+1]+ff.y-mc)
          + __expf(Kcol[4*i4+2]+ff.z-mc) + __expf(Kcol[4*i4+3]+ff.w-mc);
    }
    {
      const int parity = k & 1;
      float2* pw = (float2*)(parts) + (((size_t)parity*NB + b)*RG + rg)*NP + t;
      *pw = make_float2(mc, sc);
    }

    // ---- per-batch barrier across the 8 row-group blocks
    __syncthreads();   // each wave drains vmcnt before s_barrier -> stores at L2
    if (t == 0) {
      __hip_atomic_fetch_add(&ctr[b], 1, __ATOMIC_ACQ_REL, __HIP_MEMORY_SCOPE_AGENT);
      const int target = RG * k;
      long long spins = 0;
      while (__hip_atomic_load(&ctr[b], __ATOMIC_ACQUIRE, __HIP_MEMORY_SCOPE_AGENT) < target) {
        __builtin_amdgcn_s_sleep(2);
        if (++spins > (1LL<<30)) break;   // safety valve: fail visibly, never hang
      }
    }
    __syncthreads();
  }

  // ---- flow & ot partial: sum dist^2 * exp(f + logK + g) over my rows
  const float frow = f_lds[lrow];
  float acc = 0.f;
  #pragma unroll
  for (int cc = 0; cc < 16; ++cc) {
    const float4 g4 = g4p[8*cc + chunk];
    const float4 kk = Kreg[cc];
    const float d0 = EPSV*kk.x, d1 = EPSV*kk.y, d2 = EPSV*kk.z, d3 = EPSV*kk.w;
    acc += d0*d0*__expf(frow+kk.x+g4.x) + d1*d1*__expf(frow+kk.y+g4.y)
         + d2*d2*__expf(frow+kk.z+g4.z) + d3*d3*__expf(frow+kk.w+g4.w);
  }
  sm[t] = acc;
  __syncthreads();
  if (t < 64) {
    float v = 0.f;
    #pragma unroll
    for (int q = 0; q < 8; ++q) v += sm[t*8+q];
    #pragma unroll
    for (int o = 32; o; o >>= 1) v += __shfl_xor(v, o);
    if (t == 0) {
      const float add = v + ((rg == 0) ? (ws + WS_HUB)[b] : 0.f);
      atomicAdd(&out[b], add);
    }
  }
}

extern "C" void kernel_launch(void* const* d_in, const int* in_sizes, int n_in,
                              void* d_out, int out_size, void* d_ws, size_t ws_size,
                              hipStream_t stream) {
  const float* a_mask = (const float*)d_in[0];
  const float* pc_a   = (const float*)d_in[1];
  const float* b_mask = (const float*)d_in[2];
  const float* pc_b   = (const float*)d_in[3];
  float* out = (float*)d_out;
  float* ws  = (float*)d_ws;
  (void)in_sizes; (void)n_in; (void)out_size; (void)ws_size;

  setup_kernel<<<NB, NP, 0, stream>>>(a_mask, pc_a, b_mask, pc_b, ws, out);
  sinkhorn_kernel<<<NB*RG, NP, 0, stream>>>(pc_a, pc_b, ws, out);
}

// Round 2
// 401.762 us; speedup vs baseline: 2.1289x; 2.1289x over previous
//
#include <hip/hip_runtime.h>
#include <math.h>

#define NB 32        // batches
#define NP 512       // N == M == 512
#define RG 8         // row-groups (blocks) per batch
#define RPB 64       // rows per block
#define ITERS 50
#define NEGV  -1e9f
#define EPSV   0.05f
#define INVEPS 20.0f

// ws layout in floats
#define WS_LOGA 0
#define WS_LOGB (NB*NP)                    // 16384
#define WS_HUB  (2*NB*NP)                  // 32768 (32 used, pad to 64)
#define WS_PART (2*NB*NP + 64)             // 32832: [2][NB][RG][NP][2] floats
#define PART_FLOATS (2*NB*RG*NP*2)         // 524288
#define WS_CTR  (WS_PART + PART_FLOATS)    // 32 ints live here

// ---- relaxed agent-scope (device-coherent, NO L2 wb/inv maintenance) exchange ops ----
__device__ __forceinline__ void part_store(float2* p, float mc, float sc) {
  union { float2 f; unsigned long long u; } c;
  c.f = make_float2(mc, sc);
  __hip_atomic_store((unsigned long long*)p, c.u, __ATOMIC_RELAXED, __HIP_MEMORY_SCOPE_AGENT);
}
__device__ __forceinline__ float2 part_load(const float2* p) {
  union { unsigned long long u; float2 f; } c;
  c.u = __hip_atomic_load((const unsigned long long*)p, __ATOMIC_RELAXED, __HIP_MEMORY_SCOPE_AGENT);
  return c.f;
}

// ---------------- setup: loga/logb/huber, zero out + barrier counters ----------------
__global__ __launch_bounds__(NP) void setup_kernel(
    const float* __restrict__ a_mask, const float* __restrict__ pc_a,
    const float* __restrict__ b_mask, const float* __restrict__ pc_b,
    float* __restrict__ ws, float* __restrict__ out)
{
  __shared__ float scratch[16];
  const int b = blockIdx.x, t = threadIdx.x;
  const float apt = a_mask[b*NP+t] * pc_a[(b*NP+t)*3+2];
  const float bpt = b_mask[b*NP+t] * pc_b[(b*NP+t)*3+2];
  float ra = apt, rb = bpt;
  #pragma unroll
  for (int o = 32; o; o >>= 1) { ra += __shfl_xor(ra, o); rb += __shfl_xor(rb, o); }
  const int wid = t >> 6, lane = t & 63;
  if (lane == 0) { scratch[wid] = ra; scratch[8+wid] = rb; }
  __syncthreads();
  float asum = 0.f, bsum = 0.f;
  #pragma unroll
  for (int w = 0; w < 8; ++w) { asum += scratch[w]; bsum += scratch[8+w]; }

  ws[WS_LOGA + b*NP + t] = (apt > 0.f) ? __logf(apt/asum) : NEGV;
  ws[WS_LOGB + b*NP + t] = (bpt > 0.f) ? __logf(bpt/bsum) : NEGV;
  if (t == 0) {
    const float e = asum - bsum, ae = fabsf(e);
    ws[WS_HUB + b] = (ae <= 1.f) ? 0.5f*e*e : (ae - 0.5f);
    // counter must be reset with device-coherent store (it's polled via coherent loads)
    __hip_atomic_store((int*)(ws + WS_CTR) + b, 0, __ATOMIC_RELAXED, __HIP_MEMORY_SCOPE_AGENT);
    out[b] = 0.f;
  }
}

// ---------------- main: 50 Sinkhorn iterations + flow/ot ----------------
__global__ __launch_bounds__(NP, 2) void sinkhorn_kernel(
    const float* __restrict__ pc_a, const float* __restrict__ pc_b,
    float* __restrict__ ws, float* __restrict__ out)
{
  const int b  = blockIdx.x & 31;   // batch: blocks {b, b+32, ...} land on one XCD (perf hint only)
  const int rg = blockIdx.x >> 5;   // row-group 0..7
  const int t  = threadIdx.x;
  const int chunk = t & 7;          // row-phase column chunk
  const int lrow  = t >> 3;         // row-phase local row (0..63)
  const int grow  = rg*RPB + lrow;  // row within batch

  const float* loga = ws + WS_LOGA + (size_t)b*NP;
  const float* logb = ws + WS_LOGB + (size_t)b*NP;
  float* parts = ws + WS_PART;
  int*   ctr   = (int*)(ws + WS_CTR);

  __shared__ __align__(16) float g_lds[NP];
  __shared__ __align__(16) float logb_lds[NP];
  __shared__ __align__(16) float f_lds[RPB];
  __shared__ __align__(16) float loga_lds[RPB];
  __shared__ __align__(16) float sm[NP];
  __shared__ __align__(16) float ss[NP];

  logb_lds[t] = logb[t];
  if (t < RPB) loga_lds[t] = loga[rg*RPB + t];

  // ---- register cache of logK: row slice (row = grow, cols = 32*cc + 4*chunk + e)
  const float ax = pc_a[((size_t)b*NP+grow)*3+0];
  const float ay = pc_a[((size_t)b*NP+grow)*3+1];
  const bool  va = loga[grow] > -1e8f;
  float4 Kreg[16];
  #pragma unroll
  for (int cc = 0; cc < 16; ++cc) {
    float r[4];
    #pragma unroll
    for (int e = 0; e < 4; ++e) {
      const int col = 32*cc + 4*chunk + e;
      const float bx = pc_b[((size_t)b*NP+col)*3+0];
      const float by = pc_b[((size_t)b*NP+col)*3+1];
      const bool  vb = logb[col] > -1e8f;
      const float dx = ax-bx, dy = ay-by;
      const float d  = sqrtf(dx*dx + dy*dy + 1e-12f);
      r[e] = (va && vb) ? (-INVEPS)*d : 0.f;
    }
    Kreg[cc] = make_float4(r[0], r[1], r[2], r[3]);
  }
  // ---- register cache: column slice (col = t, rows rg*64 + i)
  const float bx0 = pc_b[((size_t)b*NP+t)*3+0];
  const float by0 = pc_b[((size_t)b*NP+t)*3+1];
  const bool  vb0 = logb[t] > -1e8f;
  float Kcol[RPB];
  #pragma unroll
  for (int i = 0; i < RPB; ++i) {
    const int row = rg*RPB + i;
    const float axi = pc_a[((size_t)b*NP+row)*3+0];   // uniform -> scalar loads
    const float ayi = pc_a[((size_t)b*NP+row)*3+1];
    const bool  vai = loga[row] > -1e8f;
    const float dx = axi-bx0, dy = ayi-by0;
    const float d  = sqrtf(dx*dx + dy*dy + 1e-12f);
    Kcol[i] = (vai && vb0) ? (-INVEPS)*d : 0.f;
  }
  __syncthreads();

  const float4* g4p = (const float4*)g_lds;
  const float4* f4p = (const float4*)f_lds;
  const float4* sm4 = (const float4*)sm;
  const float4* ss4 = (const float4*)ss;

  for (int k = 1; k <= ITERS+1; ++k) {
    // ---- combine column partials -> g_lds (logv); k==1: logv = 0
    if (k == 1) {
      g_lds[t] = 0.f;
    } else {
      const int parity = (k-1) & 1;
      const float2* pp = (const float2*)(parts) + (((size_t)parity*NB + b)*RG)*NP + t;
      float2 pr[RG];
      #pragma unroll
      for (int r = 0; r < RG; ++r) pr[r] = part_load(pp + (size_t)r*NP);
      float M = pr[0].x;
      #pragma unroll
      for (int r = 1; r < RG; ++r) M = fmaxf(M, pr[r].x);
      float S = 0.f;
      #pragma unroll
      for (int r = 0; r < RG; ++r) S += pr[r].y * __expf(pr[r].x - M);
      g_lds[t] = logb_lds[t] - (M + __logf(S));
    }
    __syncthreads();
    if (k == ITERS+1) break;   // g_lds now holds final logv

    // ---- row phase: f_i = loga_i - lse_j(logK + g)
    float m = -3.0e38f;
    #pragma unroll
    for (int cc = 0; cc < 16; ++cc) {
      const float4 g4 = g4p[8*cc + chunk];
      const float4 kk = Kreg[cc];
      m = fmaxf(m, fmaxf(fmaxf(kk.x+g4.x, kk.y+g4.y), fmaxf(kk.z+g4.z, kk.w+g4.w)));
    }
    sm[t] = m;
    __syncthreads();
    const float4 m0 = sm4[lrow*2+0], m1 = sm4[lrow*2+1];
    const float mrow = fmaxf(fmaxf(fmaxf(m0.x,m0.y),fmaxf(m0.z,m0.w)),
                             fmaxf(fmaxf(m1.x,m1.y),fmaxf(m1.z,m1.w)));
    float s = 0.f;
    #pragma unroll
    for (int cc = 0; cc < 16; ++cc) {
      const float4 g4 = g4p[8*cc + chunk];
      const float4 kk = Kreg[cc];
      s += __expf(kk.x+g4.x-mrow) + __expf(kk.y+g4.y-mrow)
         + __expf(kk.z+g4.z-mrow) + __expf(kk.w+g4.w-mrow);
    }
    ss[t] = s;
    __syncthreads();
    if (t < RPB) {
      const float4 s0 = ss4[t*2+0], s1 = ss4[t*2+1];
      const float4 q0 = sm4[t*2+0], q1 = sm4[t*2+1];
      const float mr = fmaxf(fmaxf(fmaxf(q0.x,q0.y),fmaxf(q0.z,q0.w)),
                             fmaxf(fmaxf(q1.x,q1.y),fmaxf(q1.z,q1.w)));
      const float sr = ((s0.x+s0.y)+(s0.z+s0.w)) + ((s1.x+s1.y)+(s1.z+s1.w));
      f_lds[t] = loga_lds[t] - (mr + __logf(sr));
    }
    __syncthreads();

    // ---- col phase: exact per-block (m,s) partial for column t
    float mc = -3.0e38f;
    #pragma unroll
    for (int i4 = 0; i4 < 16; ++i4) {
      const float4 ff = f4p[i4];
      mc = fmaxf(mc, fmaxf(fmaxf(Kcol[4*i4+0]+ff.x, Kcol[4*i4+1]+ff.y),
                           fmaxf(Kcol[4*i4+2]+ff.z, Kcol[4*i4+3]+ff.w)));
    }
    float sc = 0.f;
    #pragma unroll
    for (int i4 = 0; i4 < 16; ++i4) {
      const float4 ff = f4p[i4];
      sc += __expf(Kcol[4*i4+0]+ff.x-mc) + __expf(Kcol[4*i4+1]+ff.y-mc)
          + __expf(Kcol[4*i4+2]+ff.z-mc) + __expf(Kcol[4*i4+3]+ff.w-mc);
    }
    {
      const int parity = k & 1;
      float2* pw = (float2*)(parts) + (((size_t)parity*NB + b)*RG + rg)*NP + t;
      part_store(pw, mc, sc);   // device-coherent store, no cache maintenance
    }

    // ---- per-batch barrier across the 8 row-group blocks
    // __syncthreads drains each wave's vmcnt before s_barrier => all 512 partial
    // stores of this block are ack'd at the coherence point before t0's add.
    __syncthreads();
    if (t == 0) {
      __hip_atomic_fetch_add(&ctr[b], 1, __ATOMIC_RELAXED, __HIP_MEMORY_SCOPE_AGENT);
      const int target = RG * k;
      long long spins = 0;
      while (__hip_atomic_load(&ctr[b], __ATOMIC_RELAXED, __HIP_MEMORY_SCOPE_AGENT) < target) {
        __builtin_amdgcn_s_sleep(4);
        if (++spins > (1LL<<30)) break;   // safety valve: fail visibly, never hang
      }
    }
    __syncthreads();
  }

  // ---- flow & ot partial: sum dist^2 * exp(f + logK + g) over my rows
  const float frow = f_lds[lrow];
  float acc = 0.f;
  #pragma unroll
  for (int cc = 0; cc < 16; ++cc) {
    const float4 g4 = g4p[8*cc + chunk];
    const float4 kk = Kreg[cc];
    const float d0 = EPSV*kk.x, d1 = EPSV*kk.y, d2 = EPSV*kk.z, d3 = EPSV*kk.w;
    acc += d0*d0*__expf(frow+kk.x+g4.x) + d1*d1*__expf(frow+kk.y+g4.y)
         + d2*d2*__expf(frow+kk.z+g4.z) + d3*d3*__expf(frow+kk.w+g4.w);
  }
  sm[t] = acc;
  __syncthreads();
  if (t < 64) {
    float v = 0.f;
    #pragma unroll
    for (int q = 0; q < 8; ++q) v += sm[t*8+q];
    #pragma unroll
    for (int o = 32; o; o >>= 1) v += __shfl_xor(v, o);
    if (t == 0) {
      const float add = v + ((rg == 0) ? (ws + WS_HUB)[b] : 0.f);
      atomicAdd(&out[b], add);
    }
  }
}

extern "C" void kernel_launch(void* const* d_in, const int* in_sizes, int n_in,
                              void* d_out, int out_size, void* d_ws, size_t ws_size,
                              hipStream_t stream) {
  const float* a_mask = (const float*)d_in[0];
  const float* pc_a   = (const float*)d_in[1];
  const float* b_mask = (const float*)d_in[2];
  const float* pc_b   = (const float*)d_in[3];
  float* out = (float*)d_out;
  float* ws  = (float*)d_ws;
  (void)in_sizes; (void)n_in; (void)out_size; (void)ws_size;

  setup_kernel<<<NB, NP, 0, stream>>>(a_mask, pc_a, b_mask, pc_b, ws, out);
  sinkhorn_kernel<<<NB*RG, NP, 0, stream>>>(pc_a, pc_b, ws, out);
}

// Round 3
// 357.994 us; speedup vs baseline: 2.3892x; 1.1223x over previous
//
#include <hip/hip_runtime.h>
#include <math.h>

#define NB 32        // batches
#define NP 512       // N == M == 512
#define RG 8         // row-groups (blocks) per batch
#define RPB 64       // rows per block
#define ITERS 50
#define NEGV  -1e9f
#define EPSV   0.05f
#define INVEPS 20.0f

// ws layout in floats
#define WS_LOGA 0
#define WS_LOGB (NB*NP)                    // 16384
#define WS_HUB  (2*NB*NP)                  // 32768 (32 used, pad to 64)
#define WS_PART (2*NB*NP + 64)             // 32832: [2][NB][RG][NP][2] floats
#define PART_FLOATS (2*NB*RG*NP*2)         // 524288
#define WS_CTR  (WS_PART + PART_FLOATS)    // 32 ints live here

// ---- relaxed agent-scope (device-coherent, NO L2 wb/inv maintenance) exchange ops ----
__device__ __forceinline__ void part_store(float2* p, float mc, float sc) {
  union { float2 f; unsigned long long u; } c;
  c.f = make_float2(mc, sc);
  __hip_atomic_store((unsigned long long*)p, c.u, __ATOMIC_RELAXED, __HIP_MEMORY_SCOPE_AGENT);
}
__device__ __forceinline__ float2 part_load(const float2* p) {
  union { unsigned long long u; float2 f; } c;
  c.u = __hip_atomic_load((const unsigned long long*)p, __ATOMIC_RELAXED, __HIP_MEMORY_SCOPE_AGENT);
  return c.f;
}

// ---------------- setup: loga/logb/huber, zero out + barrier counters ----------------
__global__ __launch_bounds__(NP) void setup_kernel(
    const float* __restrict__ a_mask, const float* __restrict__ pc_a,
    const float* __restrict__ b_mask, const float* __restrict__ pc_b,
    float* __restrict__ ws, float* __restrict__ out)
{
  __shared__ float scratch[16];
  const int b = blockIdx.x, t = threadIdx.x;
  const float apt = a_mask[b*NP+t] * pc_a[(b*NP+t)*3+2];
  const float bpt = b_mask[b*NP+t] * pc_b[(b*NP+t)*3+2];
  float ra = apt, rb = bpt;
  #pragma unroll
  for (int o = 32; o; o >>= 1) { ra += __shfl_xor(ra, o); rb += __shfl_xor(rb, o); }
  const int wid = t >> 6, lane = t & 63;
  if (lane == 0) { scratch[wid] = ra; scratch[8+wid] = rb; }
  __syncthreads();
  float asum = 0.f, bsum = 0.f;
  #pragma unroll
  for (int w = 0; w < 8; ++w) { asum += scratch[w]; bsum += scratch[8+w]; }

  ws[WS_LOGA + b*NP + t] = (apt > 0.f) ? __logf(apt/asum) : NEGV;
  ws[WS_LOGB + b*NP + t] = (bpt > 0.f) ? __logf(bpt/bsum) : NEGV;
  if (t == 0) {
    const float e = asum - bsum, ae = fabsf(e);
    ws[WS_HUB + b] = (ae <= 1.f) ? 0.5f*e*e : (ae - 0.5f);
    __hip_atomic_store((int*)(ws + WS_CTR) + b, 0, __ATOMIC_RELAXED, __HIP_MEMORY_SCOPE_AGENT);
    out[b] = 0.f;
  }
}

// ---------------- main: 50 Sinkhorn iterations + flow/ot ----------------
// Factorized: exp(K+g-M) = expK * exp(g-M); expK precomputed in registers once.
// Row lse_i = Mg + log( sum_j expK_ij * eg_j )   (pure FMA dot)
// Col partial: m = Mf_rg (block max of f), s_j = sum_{i in rg} expK_ij * ef_i
__global__ __launch_bounds__(NP, 2) void sinkhorn_kernel(
    const float* __restrict__ pc_a, const float* __restrict__ pc_b,
    float* __restrict__ ws, float* __restrict__ out)
{
  const int b  = blockIdx.x & 31;   // batch: blocks {b, b+32, ...} land on one XCD (perf hint only)
  const int rg = blockIdx.x >> 5;   // row-group 0..7
  const int t  = threadIdx.x;
  const int chunk = t & 7;          // row-phase column chunk
  const int lrow  = t >> 3;         // row-phase local row (0..63)
  const int grow  = rg*RPB + lrow;  // row within batch
  const int lane  = t & 63, wid = t >> 6;

  const float* loga = ws + WS_LOGA + (size_t)b*NP;
  const float* logb = ws + WS_LOGB + (size_t)b*NP;
  float* parts = ws + WS_PART;
  int*   ctr   = (int*)(ws + WS_CTR);

  __shared__ __align__(16) float eg_lds[NP];   // exp(g - Mg); holds ACTUAL g after final combine
  __shared__ __align__(16) float logb_lds[NP];
  __shared__ __align__(16) float sm[NP];       // scratch for row-dot reduce / epilogue
  __shared__ __align__(16) float f_lds[RPB];   // actual f
  __shared__ __align__(16) float ef_lds[RPB];  // exp(f - Mf)
  __shared__ __align__(16) float loga_lds[RPB];
  __shared__ float wred[8];
  __shared__ float mf_s;

  logb_lds[t] = logb[t];
  if (t < RPB) loga_lds[t] = loga[rg*RPB + t];

  // ---- register cache of expK: row slice (row = grow, cols = 32*cc + 4*chunk + e)
  const float ax = pc_a[((size_t)b*NP+grow)*3+0];
  const float ay = pc_a[((size_t)b*NP+grow)*3+1];
  const bool  va = loga[grow] > -1e8f;
  float4 eKreg[16];
  #pragma unroll
  for (int cc = 0; cc < 16; ++cc) {
    float r[4];
    #pragma unroll
    for (int e = 0; e < 4; ++e) {
      const int col = 32*cc + 4*chunk + e;
      const float bx = pc_b[((size_t)b*NP+col)*3+0];
      const float by = pc_b[((size_t)b*NP+col)*3+1];
      const bool  vb = logb[col] > -1e8f;
      const float dx = ax-bx, dy = ay-by;
      const float d  = sqrtf(dx*dx + dy*dy + 1e-12f);
      r[e] = (va && vb) ? __expf((-INVEPS)*d) : 1.f;   // exp(0)=1 for masked pairs
    }
    eKreg[cc] = make_float4(r[0], r[1], r[2], r[3]);
  }
  // ---- register cache: column slice (col = t, rows rg*64 + i)
  const float bx0 = pc_b[((size_t)b*NP+t)*3+0];
  const float by0 = pc_b[((size_t)b*NP+t)*3+1];
  const bool  vb0 = logb[t] > -1e8f;
  float eKcol[RPB];
  #pragma unroll
  for (int i = 0; i < RPB; ++i) {
    const int row = rg*RPB + i;
    const float axi = pc_a[((size_t)b*NP+row)*3+0];   // uniform -> scalar loads
    const float ayi = pc_a[((size_t)b*NP+row)*3+1];
    const bool  vai = loga[row] > -1e8f;
    const float dx = axi-bx0, dy = ayi-by0;
    const float d  = sqrtf(dx*dx + dy*dy + 1e-12f);
    eKcol[i] = (vai && vb0) ? __expf((-INVEPS)*d) : 1.f;
  }
  __syncthreads();

  const float4* eg4p = (const float4*)eg_lds;
  const float4* ef4p = (const float4*)ef_lds;
  const float4* sm4  = (const float4*)sm;

  for (int k = 1; k <= ITERS+1; ++k) {
    // ---- phase A: combine column partials -> g_t for col t; k==1: g = 0
    float g_t;
    if (k == 1) {
      g_t = 0.f;
    } else {
      const int parity = (k-1) & 1;
      const float2* pp = (const float2*)(parts) + (((size_t)parity*NB + b)*RG)*NP + t;
      float2 pr[RG];
      #pragma unroll
      for (int r = 0; r < RG; ++r) pr[r] = part_load(pp + (size_t)r*NP);
      float M = pr[0].x;
      #pragma unroll
      for (int r = 1; r < RG; ++r) M = fmaxf(M, pr[r].x);
      float S = 0.f;
      #pragma unroll
      for (int r = 0; r < RG; ++r) S += pr[r].y * __expf(pr[r].x - M);
      g_t = logb_lds[t] - (M + __logf(S));
    }
    // Mg = max over all 512 cols (wave max -> cross-wave)
    float wm = g_t;
    #pragma unroll
    for (int o = 32; o; o >>= 1) wm = fmaxf(wm, __shfl_xor(wm, o));
    if (lane == 0) wred[wid] = wm;
    __syncthreads();
    float Mg = wred[0];
    #pragma unroll
    for (int w = 1; w < 8; ++w) Mg = fmaxf(Mg, wred[w]);

    if (k == ITERS+1) {           // final: publish ACTUAL g for epilogue
      eg_lds[t] = g_t;
      __syncthreads();
      break;
    }
    eg_lds[t] = __expf(g_t - Mg);
    __syncthreads();

    // ---- phase B: row dot: sum_j expK_ij * eg_j  (64 FMA/thread)
    float dot = 0.f;
    #pragma unroll
    for (int cc = 0; cc < 16; ++cc) {
      const float4 g4 = eg4p[8*cc + chunk];
      const float4 kk = eKreg[cc];
      dot += kk.x*g4.x + kk.y*g4.y + kk.z*g4.z + kk.w*g4.w;
    }
    sm[t] = dot;
    __syncthreads();
    if (t < RPB) {                 // one wave: finish rows, compute f, ef, Mf
      const float4 s0 = sm4[t*2+0], s1 = sm4[t*2+1];
      const float sr = ((s0.x+s0.y)+(s0.z+s0.w)) + ((s1.x+s1.y)+(s1.z+s1.w));
      const float f  = loga_lds[t] - (Mg + __logf(sr));
      float Mf = f;
      #pragma unroll
      for (int o = 32; o; o >>= 1) Mf = fmaxf(Mf, __shfl_xor(Mf, o));
      f_lds[t]  = f;
      ef_lds[t] = __expf(f - Mf);
      if (t == 0) mf_s = Mf;
    }
    __syncthreads();

    // ---- phase C: col dot: s_col = sum_i expK_ij * ef_i  (64 FMA/thread, broadcast reads)
    float sc = 0.f;
    #pragma unroll
    for (int i4 = 0; i4 < 16; ++i4) {
      const float4 ff = ef4p[i4];
      sc += eKcol[4*i4+0]*ff.x + eKcol[4*i4+1]*ff.y
          + eKcol[4*i4+2]*ff.z + eKcol[4*i4+3]*ff.w;
    }
    {
      const int parity = k & 1;
      float2* pw = (float2*)(parts) + (((size_t)parity*NB + b)*RG + rg)*NP + t;
      part_store(pw, mf_s, sc);    // device-coherent store, no cache maintenance
    }

    // ---- per-batch barrier across the 8 row-group blocks
    __syncthreads();   // drains vmcnt before s_barrier => partial stores ack'd
    if (t == 0) {
      __hip_atomic_fetch_add(&ctr[b], 1, __ATOMIC_RELAXED, __HIP_MEMORY_SCOPE_AGENT);
      const int target = RG * k;
      long long spins = 0;
      while (__hip_atomic_load(&ctr[b], __ATOMIC_RELAXED, __HIP_MEMORY_SCOPE_AGENT) < target) {
        __builtin_amdgcn_s_sleep(2);
        if (++spins > (1LL<<30)) break;   // safety valve: fail visibly, never hang
      }
    }
    __syncthreads();
  }

  // ---- epilogue: sum dist^2 * exp(f + K + g) over my rows
  // K reconstructed as log(expK); expK==0 => flow underflows to 0 => term 0 (matches ref).
  const float frow = f_lds[lrow];   // f from iter 50
  float acc = 0.f;
  #pragma unroll
  for (int cc = 0; cc < 16; ++cc) {
    const float4 g4 = eg4p[8*cc + chunk];   // ACTUAL g here
    const float4 kk = eKreg[cc];
    const float ek[4] = {kk.x, kk.y, kk.z, kk.w};
    const float gg[4] = {g4.x, g4.y, g4.z, g4.w};
    #pragma unroll
    for (int e = 0; e < 4; ++e) {
      const float lk = __logf(fmaxf(ek[e], 1e-38f));   // safe arg; selected away if ek==0
      const float d2 = (EPSV*lk)*(EPSV*lk);
      const float v  = d2 * __expf(frow + lk + gg[e]);
      acc += (ek[e] > 0.f) ? v : 0.f;
    }
  }
  sm[t] = acc;
  __syncthreads();
  if (t < 64) {
    float v = 0.f;
    #pragma unroll
    for (int q = 0; q < 8; ++q) v += sm[t*8+q];
    #pragma unroll
    for (int o = 32; o; o >>= 1) v += __shfl_xor(v, o);
    if (t == 0) {
      const float add = v + ((rg == 0) ? (ws + WS_HUB)[b] : 0.f);
      atomicAdd(&out[b], add);
    }
  }
}

extern "C" void kernel_launch(void* const* d_in, const int* in_sizes, int n_in,
                              void* d_out, int out_size, void* d_ws, size_t ws_size,
                              hipStream_t stream) {
  const float* a_mask = (const float*)d_in[0];
  const float* pc_a   = (const float*)d_in[1];
  const float* b_mask = (const float*)d_in[2];
  const float* pc_b   = (const float*)d_in[3];
  float* out = (float*)d_out;
  float* ws  = (float*)d_ws;
  (void)in_sizes; (void)n_in; (void)out_size; (void)ws_size;

  setup_kernel<<<NB, NP, 0, stream>>>(a_mask, pc_a, b_mask, pc_b, ws, out);
  sinkhorn_kernel<<<NB*RG, NP, 0, stream>>>(pc_a, pc_b, ws, out);
}

// Round 4
// 312.039 us; speedup vs baseline: 2.7411x; 1.1473x over previous
//
#include <hip/hip_runtime.h>
#include <math.h>

#define NB 32        // batches
#define NP 512       // N == M == 512
#define RG 16        // row-groups (blocks) per batch
#define RPB 32       // rows per block
#define ITERS 50
#define NEGV  -1e9f
#define EPSV   0.05f
#define INVEPS 20.0f

// ws layout in floats
#define WS_LOGA 0
#define WS_LOGB (NB*NP)                      // 16384
#define WS_HUB  (2*NB*NP)                    // 32768 (32 used, pad to 64)
#define WS_MF   (2*NB*NP + 64)               // 32832: [2][NB][RG] floats
#define WS_PART (WS_MF + 2*NB*RG)            // 33856: [2][NB][RG][NP] floats
#define PART_FLOATS (2*NB*RG*NP)             // 524288
#define WS_FLAG (WS_PART + PART_FLOATS)      // ints [NB][RG]

// ---- relaxed agent-scope (device-coherent, NO L2 wb/inv maintenance) ops ----
__device__ __forceinline__ void st_f32(float* p, float v) {
  __hip_atomic_store(p, v, __ATOMIC_RELAXED, __HIP_MEMORY_SCOPE_AGENT);
}
__device__ __forceinline__ float ld_f32(const float* p) {
  return __hip_atomic_load((float*)p, __ATOMIC_RELAXED, __HIP_MEMORY_SCOPE_AGENT);
}
__device__ __forceinline__ void st_i32(int* p, int v) {
  __hip_atomic_store(p, v, __ATOMIC_RELAXED, __HIP_MEMORY_SCOPE_AGENT);
}
__device__ __forceinline__ int ld_i32(const int* p) {
  return __hip_atomic_load((int*)p, __ATOMIC_RELAXED, __HIP_MEMORY_SCOPE_AGENT);
}

// ---------------- setup: loga/logb/huber, zero out + flags ----------------
__global__ __launch_bounds__(NP) void setup_kernel(
    const float* __restrict__ a_mask, const float* __restrict__ pc_a,
    const float* __restrict__ b_mask, const float* __restrict__ pc_b,
    float* __restrict__ ws, float* __restrict__ out)
{
  __shared__ float scratch[16];
  const int b = blockIdx.x, t = threadIdx.x;
  const float apt = a_mask[b*NP+t] * pc_a[(b*NP+t)*3+2];
  const float bpt = b_mask[b*NP+t] * pc_b[(b*NP+t)*3+2];
  float ra = apt, rb = bpt;
  #pragma unroll
  for (int o = 32; o; o >>= 1) { ra += __shfl_xor(ra, o); rb += __shfl_xor(rb, o); }
  const int wid = t >> 6, lane = t & 63;
  if (lane == 0) { scratch[wid] = ra; scratch[8+wid] = rb; }
  __syncthreads();
  float asum = 0.f, bsum = 0.f;
  #pragma unroll
  for (int w = 0; w < 8; ++w) { asum += scratch[w]; bsum += scratch[8+w]; }

  ws[WS_LOGA + b*NP + t] = (apt > 0.f) ? __logf(apt/asum) : NEGV;
  ws[WS_LOGB + b*NP + t] = (bpt > 0.f) ? __logf(bpt/bsum) : NEGV;
  if (t < RG) st_i32((int*)(ws + WS_FLAG) + b*RG + t, 0);
  if (t == 0) {
    const float e = asum - bsum, ae = fabsf(e);
    ws[WS_HUB + b] = (ae <= 1.f) ? 0.5f*e*e : (ae - 0.5f);
    out[b] = 0.f;
  }
}

// ---------------- main: 50 Sinkhorn iterations + flow/ot ----------------
// RG=16 blocks/batch, 32 rows each; 2 blocks/CU so barrier spins are hidden
// by a co-resident block of a DIFFERENT batch (b = bid>>4 => pair b, b+16).
__global__ __launch_bounds__(NP, 4) void sinkhorn_kernel(
    const float* __restrict__ pc_a, const float* __restrict__ pc_b,
    float* __restrict__ ws, float* __restrict__ out)
{
  const int bid = blockIdx.x;
  const int b   = bid >> 4;          // batch
  const int rg  = bid & 15;          // row-group 0..15
  const int t   = threadIdx.x;
  const int chunk = t & 15;          // row-phase column chunk (32 cols)
  const int lrow  = t >> 4;          // row-phase local row (0..31)
  const int grow  = rg*RPB + lrow;   // row within batch
  const int lane  = t & 63, wid = t >> 6;

  const float* loga = ws + WS_LOGA + (size_t)b*NP;
  const float* logb = ws + WS_LOGB + (size_t)b*NP;
  float* parts = ws + WS_PART;
  float* mfg   = ws + WS_MF;
  int*   flags = (int*)(ws + WS_FLAG);

  __shared__ __align__(16) float eg_lds[NP];   // exp(g - Mg); raw g after final combine
  __shared__ __align__(16) float logb_lds[NP];
  __shared__ __align__(16) float sm[NP];       // row-dot reduce / epilogue scratch
  __shared__ __align__(16) float f_lds[RPB];   // actual f
  __shared__ __align__(16) float ef_lds[RPB];  // exp(f - Mf)
  __shared__ __align__(16) float loga_lds[RPB];
  __shared__ float mf_lds[RG];
  __shared__ float wred[8];
  __shared__ float mf_s;

  logb_lds[t] = logb[t];
  if (t < RPB) loga_lds[t] = loga[rg*RPB + t];

  // ---- register cache of expK: row slice (row = grow, cols = 64*cc + 4*chunk + e)
  const float ax = pc_a[((size_t)b*NP+grow)*3+0];
  const float ay = pc_a[((size_t)b*NP+grow)*3+1];
  const bool  va = loga[grow] > -1e8f;
  float4 eKreg[8];
  #pragma unroll
  for (int cc = 0; cc < 8; ++cc) {
    float r[4];
    #pragma unroll
    for (int e = 0; e < 4; ++e) {
      const int col = 64*cc + 4*chunk + e;
      const float bx = pc_b[((size_t)b*NP+col)*3+0];
      const float by = pc_b[((size_t)b*NP+col)*3+1];
      const bool  vb = logb[col] > -1e8f;
      const float dx = ax-bx, dy = ay-by;
      const float d  = sqrtf(dx*dx + dy*dy + 1e-12f);
      r[e] = (va && vb) ? __expf((-INVEPS)*d) : 1.f;   // exp(0)=1 for masked pairs
    }
    eKreg[cc] = make_float4(r[0], r[1], r[2], r[3]);
  }
  // ---- register cache: column slice (col = t, rows rg*32 + i)
  const float bx0 = pc_b[((size_t)b*NP+t)*3+0];
  const float by0 = pc_b[((size_t)b*NP+t)*3+1];
  const bool  vb0 = logb[t] > -1e8f;
  float eKcol[RPB];
  #pragma unroll
  for (int i = 0; i < RPB; ++i) {
    const int row = rg*RPB + i;
    const float axi = pc_a[((size_t)b*NP+row)*3+0];   // uniform -> scalar loads
    const float ayi = pc_a[((size_t)b*NP+row)*3+1];
    const bool  vai = loga[row] > -1e8f;
    const float dx = axi-bx0, dy = ayi-by0;
    const float d  = sqrtf(dx*dx + dy*dy + 1e-12f);
    eKcol[i] = (vai && vb0) ? __expf((-INVEPS)*d) : 1.f;
  }
  __syncthreads();

  const float4* eg4p = (const float4*)eg_lds;
  const float4* ef4p = (const float4*)ef_lds;
  const float4* sm4  = (const float4*)sm;

  for (int k = 1; k <= ITERS+1; ++k) {
    // ---- phase A: combine column partials -> g_t for col t; k==1: g = 0
    float g_t;
    if (k == 1) {
      g_t = 0.f;
    } else {
      const int parity = (k-1) & 1;
      const float* sp = parts + (((size_t)parity*NB + b)*RG)*NP + t;
      float sv[RG];
      #pragma unroll
      for (int r = 0; r < RG; ++r) sv[r] = ld_f32(sp + (size_t)r*NP);
      float M = mf_lds[0];                       // loaded by poll threads last iter
      #pragma unroll
      for (int r = 1; r < RG; ++r) M = fmaxf(M, mf_lds[r]);
      float S = 0.f;
      #pragma unroll
      for (int r = 0; r < RG; ++r) S += sv[r] * __expf(mf_lds[r] - M);
      g_t = logb_lds[t] - (M + __logf(S));
    }
    // Mg = max over all 512 cols
    float wm = g_t;
    #pragma unroll
    for (int o = 32; o; o >>= 1) wm = fmaxf(wm, __shfl_xor(wm, o));
    if (lane == 0) wred[wid] = wm;
    __syncthreads();
    float Mg = wred[0];
    #pragma unroll
    for (int w = 1; w < 8; ++w) Mg = fmaxf(Mg, wred[w]);

    if (k == ITERS+1) {           // final: publish ACTUAL g for epilogue
      eg_lds[t] = g_t;
      __syncthreads();
      break;
    }
    eg_lds[t] = __expf(g_t - Mg);
    __syncthreads();

    // ---- phase B: row dot: sum_j expK_ij * eg_j  (32 FMA/thread)
    float dot = 0.f;
    #pragma unroll
    for (int cc = 0; cc < 8; ++cc) {
      const float4 g4 = eg4p[16*cc + chunk];
      const float4 kk = eKreg[cc];
      dot += kk.x*g4.x + kk.y*g4.y + kk.z*g4.z + kk.w*g4.w;
    }
    sm[t] = dot;
    __syncthreads();
    if (t < 64) {                  // wave 0: finish rows, compute f, ef, Mf
      float f = -3.0e38f;
      if (t < RPB) {
        const float4 s0 = sm4[4*t+0], s1 = sm4[4*t+1], s2 = sm4[4*t+2], s3 = sm4[4*t+3];
        const float sr = ((s0.x+s0.y)+(s0.z+s0.w)) + ((s1.x+s1.y)+(s1.z+s1.w))
                       + ((s2.x+s2.y)+(s2.z+s2.w)) + ((s3.x+s3.y)+(s3.z+s3.w));
        f = loga_lds[t] - (Mg + __logf(sr));
      }
      float Mf = f;
      #pragma unroll
      for (int o = 32; o; o >>= 1) Mf = fmaxf(Mf, __shfl_xor(Mf, o));
      if (t < RPB) { f_lds[t] = f; ef_lds[t] = __expf(f - Mf); }
      if (t == 0) mf_s = Mf;
    }
    __syncthreads();

    // ---- phase C: col dot: s_col = sum_i expK_ij * ef_i  (32 FMA/thread)
    float sc = 0.f;
    #pragma unroll
    for (int i4 = 0; i4 < 8; ++i4) {
      const float4 ff = ef4p[i4];
      sc += eKcol[4*i4+0]*ff.x + eKcol[4*i4+1]*ff.y
          + eKcol[4*i4+2]*ff.z + eKcol[4*i4+3]*ff.w;
    }
    {
      const int parity = k & 1;
      st_f32(parts + (((size_t)parity*NB + b)*RG + rg)*NP + t, sc);
      if (t == 0) st_f32(mfg + ((size_t)parity*NB + b)*RG + rg, mf_s);
    }

    // ---- per-batch barrier across 16 blocks: flag-publish + parallel poll.
    // __syncthreads drains each wave's vmcnt before s_barrier => all s/Mf
    // stores of this block are ack'd at the coherence point before the flag.
    __syncthreads();
    if (t == 0) st_i32(flags + b*RG + rg, k);
    if (t < RG) {
      long long spins = 0;
      while (ld_i32(flags + b*RG + t) < k) {
        __builtin_amdgcn_s_sleep(2);
        if (++spins > (1LL<<30)) break;   // safety valve: fail visibly, never hang
      }
      // publisher's Mf store precedes its flag => safe to read now
      mf_lds[t] = ld_f32(mfg + ((size_t)(k & 1)*NB + b)*RG + t);
    }
    __syncthreads();
  }

  // ---- epilogue: sum dist^2 * exp(f + K + g) over my rows
  // K reconstructed as log(expK); expK==0 => flow underflows to 0 (matches ref).
  const float frow = f_lds[lrow];   // f from iter 50
  float acc = 0.f;
  #pragma unroll
  for (int cc = 0; cc < 8; ++cc) {
    const float4 g4 = eg4p[16*cc + chunk];   // ACTUAL g here
    const float4 kk = eKreg[cc];
    const float ek[4] = {kk.x, kk.y, kk.z, kk.w};
    const float gg[4] = {g4.x, g4.y, g4.z, g4.w};
    #pragma unroll
    for (int e = 0; e < 4; ++e) {
      const float lk = __logf(fmaxf(ek[e], 1e-38f));   // safe arg; selected away if ek==0
      const float d2 = (EPSV*lk)*(EPSV*lk);
      const float v  = d2 * __expf(frow + lk + gg[e]);
      acc += (ek[e] > 0.f) ? v : 0.f;
    }
  }
  sm[t] = acc;
  __syncthreads();
  if (t < 64) {
    float v = 0.f;
    #pragma unroll
    for (int q = 0; q < 8; ++q) v += sm[t*8+q];
    #pragma unroll
    for (int o = 32; o; o >>= 1) v += __shfl_xor(v, o);
    if (t == 0) {
      const float add = v + ((rg == 0) ? (ws + WS_HUB)[b] : 0.f);
      atomicAdd(&out[b], add);
    }
  }
}

extern "C" void kernel_launch(void* const* d_in, const int* in_sizes, int n_in,
                              void* d_out, int out_size, void* d_ws, size_t ws_size,
                              hipStream_t stream) {
  const float* a_mask = (const float*)d_in[0];
  const float* pc_a   = (const float*)d_in[1];
  const float* b_mask = (const float*)d_in[2];
  const float* pc_b   = (const float*)d_in[3];
  float* out = (float*)d_out;
  float* ws  = (float*)d_ws;
  (void)in_sizes; (void)n_in; (void)out_size; (void)ws_size;

  setup_kernel<<<NB, NP, 0, stream>>>(a_mask, pc_a, b_mask, pc_b, ws, out);
  sinkhorn_kernel<<<NB*RG, NP, 0, stream>>>(pc_a, pc_b, ws, out);
}